// Round 5
// baseline (190.828 us; speedup 1.0000x reference)
//
#include <hip/hip_runtime.h>

#define NUM_BINS 9900
#define ROW_P    1024
#define BLOCK    512

__global__ __launch_bounds__(BLOCK) void binned_spectra_kernel(
    const float* __restrict__ mz,
    const float* __restrict__ inten,
    float* __restrict__ out)
{
    __shared__ float hist[NUM_BINS];

    const int row = blockIdx.x;
    const int tid = threadIdx.x;

    for (int j = tid; j < NUM_BINS; j += BLOCK) hist[j] = 0.0f;
    __syncthreads();

    const float* __restrict__ mzr = mz    + (size_t)row * ROW_P;
    const float* __restrict__ inr = inten + (size_t)row * ROW_P;

    #pragma unroll
    for (int k = 0; k < ROW_P / BLOCK; ++k) {
        const int p = tid + k * BLOCK;
        const float m = mzr[p];
        const float v = inr[p];
        if (m >= 10.0f && m < 1000.0f) {
            // Match XLA-lowered binning: divide-by-0.1f is algebraically
            // simplified to multiply by fp32(1/0.1f) == 10.0f exactly.
            // Strict fp32 sub + mul (not FMA-fusable), truncating cast, clip.
            const float u = (m - 10.0f) * 10.0f;
            int idx = (int)u;
            idx = idx < 0 ? 0 : (idx > NUM_BINS - 1 ? NUM_BINS - 1 : idx);
            atomicAdd(&hist[idx], __fsqrt_rn(v));
        }
    }
    __syncthreads();

    float* __restrict__ outr = out + (size_t)row * NUM_BINS;
    for (int j = tid; j < NUM_BINS; j += BLOCK) outr[j] = hist[j];
}

extern "C" void kernel_launch(void* const* d_in, const int* in_sizes, int n_in,
                              void* d_out, int out_size, void* d_ws, size_t ws_size,
                              hipStream_t stream)
{
    const float* mz    = (const float*)d_in[0];
    const float* inten = (const float*)d_in[1];
    float* out = (float*)d_out;

    const int rows = in_sizes[0] / ROW_P;  // 4096
    binned_spectra_kernel<<<rows, BLOCK, 0, stream>>>(mz, inten, out);
}